// Round 5
// baseline (23.061 us; speedup 1.0000x reference)
//
#include <hip/hip_runtime.h>

#define NN 512
typedef unsigned long long u64;

// ---------- k1: per-row (one wave): m-mask -> remove mask + own-filtered keep mask ----------
__global__ __launch_bounds__(64, 1) void k_remove(const float* __restrict__ adj,
                                                  u64* __restrict__ rm,
                                                  u64* __restrict__ keep1) {
    int lane = threadIdx.x;
    int r = blockIdx.x;                 // b*N + i
    int i = r & (NN - 1);
    const float* row = adj + (size_t)r * NN;

    u64 mw[8];
    #pragma unroll
    for (int q = 0; q < 8; ++q) {
        int j = q * 64 + lane;
        mw[q] = __ballot((j != i) && (row[j] > 0.0f));
    }
    int num = 0;
    #pragma unroll
    for (int q = 0; q < 8; ++q) num += __popcll(mw[q]);
    int skip = (num > 10) ? ((num + 1) >> 1) : 1;   // T_THRESH=10, K_DIL=2

    u64 lm = (1ULL << lane) - 1ULL;
    u64 rw = 0, kw = 0;
    int pre = 0;
    #pragma unroll
    for (int q = 0; q < 8; ++q) {
        bool m = (mw[q] >> lane) & 1ULL;
        int rel = pre + __popcll(mw[q] & lm);       // rank among m-entries
        bool rem = m && (skip > 1) && (rel % skip == skip - 1);
        u64 rb = __ballot(rem);
        if (lane == q) { rw = rb; kw = mw[q] & ~rb; }
        pre += __popcll(mw[q]);
    }
    if (lane < 8) {
        rm[(size_t)r * 8 + lane]    = rw;
        keep1[(size_t)r * 8 + lane] = kw;
    }
}

// ---------- in-register bitonic sorting network (compile-time indices) ----------
template<int NS>
__device__ __forceinline__ void sort_net(float* v) {
    #pragma unroll
    for (int k = 2; k <= NS; k <<= 1) {
        #pragma unroll
        for (int j = k >> 1; j > 0; j >>= 1) {
            #pragma unroll
            for (int i = 0; i < NS; ++i) {
                int ixj = i ^ j;
                if (ixj > i) {
                    float a = v[i], c = v[ixj];
                    float mn = fminf(a, c), mx = fmaxf(a, c);
                    if ((i & k) == 0) { v[i] = mn; v[ixj] = mx; }
                    else              { v[i] = mx; v[ixj] = mn; }
                }
            }
        }
    }
}

// gather all candidates, +inf-mask the removed ones (bit a of km), sort, emit window
template<int NS>
__device__ __forceinline__ void gather_sort_win(const float* __restrict__ xb,
                                                const int* jl, u64 km, int ct,
                                                float* win, int lane,
                                                int kmin, int kmax) {
    float v[NS];
    #pragma unroll
    for (int a = 0; a < NS; ++a) {
        float g = __builtin_inff();
        if (a < ct) g = xb[(size_t)jl[a] * 64 + lane];    // uniform branch, coalesced 256B
        v[a] = ((km >> a) & 1ULL) ? g : __builtin_inff(); // removed -> +inf (matches ref pad)
    }
    sort_net<NS>(v);
    #pragma unroll
    for (int a = 0; a < NS; ++a)
        if (a >= kmin && a <= kmax)                       // uniform: only window written
            win[(a - kmin) * 64 + lane] = v[a];
}

// ---------- k2: per-row (one wave): neighbors, quantiles, GEMV, L2-norm ----------
__global__ __launch_bounds__(64, 1) void k_quant(const float* __restrict__ x,
                                                 const float* __restrict__ Wl,
                                                 const float* __restrict__ bl,
                                                 const float* __restrict__ Wr,
                                                 const u64* __restrict__ rm,
                                                 const u64* __restrict__ keep1,
                                                 float* __restrict__ out) {
    __shared__ float win[34 * 64];      // quantile window (max width 34); reused for GEMV bcast
    __shared__ int   jl[72];            // candidate list (keep1 survivors + self), fast path
    __shared__ int   jls[512];          // slow-path kept list (statistically unreachable)
    int lane = threadIdx.x;
    int r = blockIdx.x;
    int b = r >> 9, i = r & (NN - 1);
    const float* xb = x + (size_t)b * NN * 64;

    // uniform scalar loads of own-filtered keep mask
    u64 k1w[8];
    #pragma unroll
    for (int q = 0; q < 8; ++q) k1w[q] = keep1[(size_t)r * 8 + q];

    // rank-select candidate list
    u64 lm = (1ULL << lane) - 1ULL;
    int pre = 0;
    #pragma unroll
    for (int q = 0; q < 8; ++q) {
        if ((k1w[q] >> lane) & 1ULL) {
            int rank = pre + __popcll(k1w[q] & lm);
            if (rank < 71) jl[rank] = q * 64 + lane;
        }
        pre += __popcll(k1w[q]);
    }
    int ct1 = pre;                      // candidates excluding self
    if (lane == 0 && ct1 < 71) jl[ct1] = i;   // append self
    __syncthreads();

    int iw = i >> 6, ib2 = i & 63;
    // reverse-direction remove bits, issued ASAP (overlaps with the x gather below)
    bool kp = false;
    if (lane < ct1 && lane < 64) {
        u64 rmj = rm[((size_t)(b * NN + jl[lane])) * 8 + iw];
        kp = !((rmj >> ib2) & 1ULL);
    }
    u64 km = __ballot(kp);

    float xi = xb[(size_t)i * 64 + lane];
    int ct = ct1 + 1;

    float qv[6];
    float fr0, fr1, fr2;
    if (ct <= 64) {
        km |= (1ULL << ct1);            // self always kept
        int deg = __popcll(km);
        float pm = fmaxf((float)deg - 1.0f, 0.0f);
        float pos0 = 0.25f * pm, pos1 = 0.5f * pm, pos2 = 0.75f * pm;
        float l0 = floorf(pos0), l1 = floorf(pos1), l2 = floorf(pos2);
        fr0 = pos0 - l0; fr1 = pos1 - l1; fr2 = pos2 - l2;
        int kks[6] = {(int)l0, (int)ceilf(pos0), (int)l1, (int)ceilf(pos1),
                      (int)l2, (int)ceilf(pos2)};
        int kmin = kks[0], kmax = kks[5];   // width <= 34 for deg <= 64

        if (ct <= 32) gather_sort_win<32>(xb, jl, km, ct, win, lane, kmin, kmax);
        else          gather_sort_win<64>(xb, jl, km, ct, win, lane, kmin, kmax);
        #pragma unroll
        for (int q = 0; q < 6; ++q) qv[q] = win[(kks[q] - kmin) * 64 + lane];
    } else {
        // slow safe path: rebuild full kept list, O(deg^2) rank count on global reads
        int pre2 = 0;
        #pragma unroll
        for (int q = 0; q < 8; ++q) {
            int j = q * 64 + lane;
            bool cand = (k1w[q] >> lane) & 1ULL;
            u64 rmj2 = 0;
            if (cand) rmj2 = rm[((size_t)(b * NN + j)) * 8 + iw];
            bool kp2 = cand && !((rmj2 >> ib2) & 1ULL);
            u64 kq = __ballot(kp2);
            if (kp2) jls[pre2 + __popcll(kq & lm)] = j;
            pre2 += __popcll(kq);
        }
        if (lane == 0) jls[pre2] = i;
        __syncthreads();
        int deg = pre2 + 1;
        float pm = fmaxf((float)deg - 1.0f, 0.0f);
        float pos0 = 0.25f * pm, pos1 = 0.5f * pm, pos2 = 0.75f * pm;
        float l0 = floorf(pos0), l1 = floorf(pos1), l2 = floorf(pos2);
        fr0 = pos0 - l0; fr1 = pos1 - l1; fr2 = pos2 - l2;
        int kks[6] = {(int)l0, (int)ceilf(pos0), (int)l1, (int)ceilf(pos1),
                      (int)l2, (int)ceilf(pos2)};
        for (int a2 = 0; a2 < deg; ++a2) {
            float v1 = xb[(size_t)jls[a2] * 64 + lane];
            int cl = 0, ce = 0;
            for (int c = 0; c < deg; ++c) {
                float u = xb[(size_t)jls[c] * 64 + lane];
                cl += (u < v1); ce += (u == v1);
            }
            #pragma unroll
            for (int q = 0; q < 6; ++q)
                if (cl <= kks[q] && kks[q] < cl + ce) qv[q] = v1;
        }
    }

    float agg = 0.25f * (qv[0] * (1.0f - fr0) + qv[1] * fr0)
              + 0.50f * (qv[2] * (1.0f - fr1) + qv[3] * fr1)
              + 0.25f * (qv[4] * (1.0f - fr2) + qv[5] * fr2);

    // GEMV: o_f = b_f + sum_k agg_k*Wl[k,f] + xi_k*Wr[k,f]
    __syncthreads();                    // qv reads done before win overwrite
    win[lane] = agg;
    win[64 + lane] = xi;
    __syncthreads();
    float o = bl[lane];
    #pragma unroll
    for (int k = 0; k < 64; ++k)
        o += win[k] * Wl[k * 64 + lane] + win[64 + k] * Wr[k * 64 + lane];

    float ss = o * o;
    #pragma unroll
    for (int off = 32; off >= 1; off >>= 1) ss += __shfl_xor(ss, off);
    out[(size_t)r * 64 + lane] = o / fmaxf(sqrtf(ss), 1e-12f);
}

extern "C" void kernel_launch(void* const* d_in, const int* in_sizes, int n_in,
                              void* d_out, int out_size, void* d_ws, size_t ws_size,
                              hipStream_t stream) {
    const float* x   = (const float*)d_in[0];
    const float* adj = (const float*)d_in[1];
    const float* Wl  = (const float*)d_in[2];
    const float* bl  = (const float*)d_in[3];
    const float* Wr  = (const float*)d_in[4];
    float* out = (float*)d_out;

    int B = in_sizes[0] / (NN * 64);            // 4
    u64* rm    = (u64*)d_ws;                     // B*N*8 u64 = 128 KB
    u64* keep1 = rm + (size_t)B * NN * 8;        // another 128 KB

    k_remove<<<dim3(B * NN), dim3(64), 0, stream>>>(adj, rm, keep1);
    k_quant <<<dim3(B * NN), dim3(64), 0, stream>>>(x, Wl, bl, Wr, rm, keep1, out);
}